// Round 7
// baseline (969.721 us; speedup 1.0000x reference)
//
#include <hip/hip_runtime.h>
#include <cstdint>
#include <cstddef>

// Problem constants
#define NB 256
#define SQ 500
#define NROWS (NB * SQ)   // 128000
#define DQ 128
#define DV 256
#define MM 50
#define FF 512
#define WSTRIDE 64        // padded w-row stride (cols 50..63 zero)

typedef _Float16 half8 __attribute__((ext_vector_type(8)));
typedef float floatx4 __attribute__((ext_vector_type(4)));
typedef unsigned short u16;
typedef unsigned int u32;

__device__ __forceinline__ float4 ld4(const float* p) {
    return *reinterpret_cast<const float4*>(p);
}
__device__ __forceinline__ float sigf(float x) { return 1.f / (1.f + __expf(-x)); }
__device__ __forceinline__ float tanhfast(float x) { return 2.f / (1.f + __expf(-2.f * x)) - 1.f; }
__device__ __forceinline__ int gmap(int l, int s0, int CS) {
    int b = (unsigned)l / (unsigned)CS;
    return b * SQ + s0 + (l - b * CS);
}
__device__ __forceinline__ void st4h(u16* dst, float4 v) {
    _Float16 h0 = (_Float16)v.x, h1 = (_Float16)v.y, h2 = (_Float16)v.z, h3 = (_Float16)v.w;
    ushort4 u;
    u.x = *(u16*)&h0; u.y = *(u16*)&h1; u.z = *(u16*)&h2; u.w = *(u16*)&h3;
    *(ushort4*)dst = u;
}
__device__ __forceinline__ float h2f(u16 b) { _Float16 h; *(u16*)&h = b; return (float)h; }
__device__ __forceinline__ u16 f2h(float x) { _Float16 h = (_Float16)x; return *(u16*)&h; }

// ---------------------------------------------------------------------------
// fp32 -> fp16 conversion (vec4)
// ---------------------------------------------------------------------------
__global__ __launch_bounds__(256) void cvt16(
    const float* __restrict__ s, u16* __restrict__ d, int n4)
{
    int i = blockIdx.x * 256 + threadIdx.x;
    if (i < n4) st4h(d + 4 * (size_t)i, ld4(s + 4 * (size_t)i));
}

// ---------------------------------------------------------------------------
// Mk [50,128] fp32 -> Mkh [64,128] fp16, rows 50..63 zeroed
// ---------------------------------------------------------------------------
__global__ __launch_bounds__(256) void mkcvt(
    const float* __restrict__ Mk, u16* __restrict__ Mkh)
{
    int i = blockIdx.x * 256 + threadIdx.x;   // 2048 float4 slots
    if (i >= 64 * 32) return;
    int row = i >> 5;
    float4 v = (row < MM) ? ld4(Mk + (size_t)row * DQ + (i & 31) * 4)
                          : float4{0.f, 0.f, 0.f, 0.f};
    st4h(Mkh + 4 * (size_t)i, v);
}

// ---------------------------------------------------------------------------
// prep: Xp rows [0,Nc) = fp16(te+qe); rows [Nc,2Nc) = fp16(he+hte+ae+qe);
//       S3p = fp16(he+hte+ae); QEp = fp16(qe)
// ---------------------------------------------------------------------------
__global__ __launch_bounds__(256) void prep128(
    const int* __restrict__ q_data, const int* __restrict__ time_data,
    const int* __restrict__ attempt_data, const int* __restrict__ hint_data,
    const int* __restrict__ hintT_data,
    const float* __restrict__ q_emb, const float* __restrict__ time_emb,
    const float* __restrict__ attempt_emb, const float* __restrict__ ht_emb,
    u16* __restrict__ Xp, u16* __restrict__ S3p, u16* __restrict__ QEp,
    int s0, int CS, int Nc)
{
    int g = blockIdx.x * 256 + threadIdx.x;
    int l = g >> 5;
    int kq = (g & 31) << 2;
    if (l >= Nc) return;
    int n = gmap(l, s0, CS);
    float4 qe  = ld4(q_emb       + (size_t)q_data[n]       * DQ + kq);
    float4 te  = ld4(time_emb    + (size_t)time_data[n]    * DQ + kq);
    float4 ae  = ld4(attempt_emb + (size_t)attempt_data[n] * DQ + kq);
    float4 he  = ld4(ht_emb      + (size_t)hint_data[n]    * DQ + kq);
    float4 hte = ld4(ht_emb      + (size_t)hintT_data[n]   * DQ + kq);
    size_t off = (size_t)l * DQ + kq;
    float4 x1, s3, x2;
    x1.x = te.x + qe.x; x1.y = te.y + qe.y; x1.z = te.z + qe.z; x1.w = te.w + qe.w;
    s3.x = he.x + hte.x + ae.x; s3.y = he.y + hte.y + ae.y;
    s3.z = he.z + hte.z + ae.z; s3.w = he.w + hte.w + ae.w;
    x2.x = s3.x + qe.x; x2.y = s3.y + qe.y; x2.z = s3.z + qe.z; x2.w = s3.w + qe.w;
    st4h(Xp + off, x1);
    st4h(Xp + (size_t)Nc * DQ + off, x2);
    st4h(S3p + off, s3);
    st4h(QEp + off, qe);
}

// ---------------------------------------------------------------------------
// fp16 MFMA GEMM: Y = epi(act(A @ W^T + bias)), BM=BN=128, BK=32, 4 waves,
// wave tile 64x64 = 4x4 of v_mfma_f32_16x16x32_f16.
// MODE 1: tanh -> fp16 Yh (stride 128)               [lin1 on 2Nc rows]
// MODE 2: sig; row<Nc: tf->Yh; row>=Nc: x3=qe+v*s3 -> Yh  [lin2 batched]
// MODE 3: none; qp->Yh; fused ie=qp+tf*te -> AUX[,256:384] [lin1(X3)+ew_ie]
// MODE 4: gather A=qaE[idx]; by<2: sig->e, else tanh->a; packed u16 pairs->AUX
// MODE 5: tanh(rc); pred-partial reduce -> atomicAdd Yf    [readout+pred]
// ---------------------------------------------------------------------------
template <int MODE>
__global__ __launch_bounds__(256, 3) void gemm16(
    const u16* __restrict__ A, const u16* __restrict__ W0,
    const u16* __restrict__ W1, const float* __restrict__ b0,
    const float* __restrict__ b1, u16* __restrict__ Yh,
    float* __restrict__ Yf,
    const u16* __restrict__ QEp, const u16* __restrict__ S3p,
    const int* __restrict__ idx, const float* __restrict__ gtab,
    u16* __restrict__ AUX, const float* __restrict__ predW,
    int K, int Nc, int s0, int CS)
{
    __shared__ u16 smem[2 * 128 * 40];   // 20480 B: A-tile | B-tile (pitch 80B)
    u16* At = smem;
    u16* Bt = smem + 128 * 40;
    const int tid = threadIdx.x;
    const int row0 = blockIdx.x * 128;
    const int by = blockIdx.y;

    const u16* Wp;
    int col0;
    if constexpr (MODE == 4) { Wp = (by < 2) ? W0 : W1; col0 = (by & 1) * 128; }
    else { Wp = W0; col0 = by * 128; }
    const float* bias = (MODE == 4 && by >= 2) ? b1 : b0;

    floatx4 acc[4][4];
#pragma unroll
    for (int m = 0; m < 4; ++m)
#pragma unroll
        for (int n = 0; n < 4; ++n) acc[m][n] = (floatx4)0.f;

    const int lane = tid & 63, wv = tid >> 6;
    const int wr = (wv >> 1) * 64, wc = (wv & 1) * 64;
    const int q = lane >> 4, c0 = lane & 15;

    for (int kt = 0; kt < K; kt += 32) {
#pragma unroll
        for (int i = 0; i < 4; ++i) {
            int c = tid + i * 256;          // [0,1024)
            if (c < 512) {
                int r = c >> 2, seg = c & 3;
                const u16* src;
                if constexpr (MODE == 4) {
                    int g = idx[gmap(row0 + r, s0, CS)];
                    src = A + (size_t)g * K + kt + seg * 8;
                } else {
                    src = A + (size_t)(row0 + r) * K + kt + seg * 8;
                }
                *(uint4*)&At[r * 40 + seg * 8] = *(const uint4*)src;
            } else {
                int cb = c - 512;
                int r = cb >> 2, seg = cb & 3;
                const u16* src = Wp + (size_t)(col0 + r) * K + kt + seg * 8;
                *(uint4*)&Bt[r * 40 + seg * 8] = *(const uint4*)src;
            }
        }
        __syncthreads();
        half8 af[4], bf[4];
#pragma unroll
        for (int m = 0; m < 4; ++m) af[m] = *(half8*)&At[(wr + m * 16 + c0) * 40 + q * 8];
#pragma unroll
        for (int n = 0; n < 4; ++n) bf[n] = *(half8*)&Bt[(wc + n * 16 + c0) * 40 + q * 8];
#pragma unroll
        for (int m = 0; m < 4; ++m)
#pragma unroll
            for (int n = 0; n < 4; ++n)
                acc[m][n] = __builtin_amdgcn_mfma_f32_16x16x32_f16(af[m], bf[n], acc[m][n], 0, 0, 0);
        __syncthreads();
    }

    float bv[4];
#pragma unroll
    for (int n = 0; n < 4; ++n) bv[n] = bias[col0 + wc + n * 16 + c0];

    if constexpr (MODE == 5) {
        float pw[4];
#pragma unroll
        for (int n = 0; n < 4; ++n) pw[n] = predW[col0 + wc + n * 16 + c0];
        float* red = (float*)smem;          // [128][33] = 16896 B <= 20480
#pragma unroll
        for (int m = 0; m < 4; ++m)
#pragma unroll
            for (int r4 = 0; r4 < 4; ++r4) {
                int row = wr + m * 16 + q * 4 + r4;
                float pp = 0.f;
#pragma unroll
                for (int n = 0; n < 4; ++n)
                    pp = fmaf(tanhfast(acc[m][n][r4] + bv[n]), pw[n], pp);
                red[row * 33 + (wv & 1) * 16 + c0] = pp;
            }
        __syncthreads();
        if (tid < 128) {
            float s = 0.f;
#pragma unroll
            for (int j = 0; j < 32; ++j) s += red[tid * 33 + j];
            atomicAdd(&Yf[row0 + tid], s);
        }
    } else {
#pragma unroll
        for (int m = 0; m < 4; ++m)
#pragma unroll
            for (int r4 = 0; r4 < 4; ++r4) {
                int row = row0 + wr + m * 16 + q * 4 + r4;
#pragma unroll
                for (int n = 0; n < 4; ++n) {
                    int col = col0 + wc + n * 16 + c0;
                    float v = acc[m][n][r4] + bv[n];
                    if constexpr (MODE == 1) {
                        Yh[(size_t)row * 128 + col] = f2h(tanhfast(v));
                    } else if constexpr (MODE == 2) {
                        v = sigf(v);
                        if (row < Nc) {
                            Yh[(size_t)row * 128 + col] = f2h(v);
                        } else {
                            size_t o = (size_t)(row - Nc) * 128 + col;
                            float qe = h2f(QEp[o]), s3 = h2f(S3p[o]);
                            Yh[(size_t)row * 128 + col] = f2h(fmaf(v, s3, qe));
                        }
                    } else if constexpr (MODE == 3) {
                        size_t o = (size_t)row * 128 + col;
                        float tf = h2f(Yh[o]);   // read tf BEFORE overwriting with qp
                        float te = gtab[(size_t)idx[gmap(row, s0, CS)] * 128 + col];
                        AUX[(size_t)row * 384 + 256 + col] = f2h(fmaf(tf, te, v));
                        Yh[o] = f2h(v);
                    } else { // MODE 4
                        bool isE = (by < 2);
                        v = isE ? sigf(v) : tanhfast(v);
                        AUX[((size_t)row * 256 + col) * 2 + (isE ? 0 : 1)] = f2h(v);
                    }
                }
            }
    }
}

// ---------------------------------------------------------------------------
// w = softmax(qp @ Mk^T) via MFMA. Block: 128 rows x 64 cols (50 live).
// Logits -> LDS (pitch 67), row softmax, zero cols 50..63, coalesced store
// to Wb (stride WSTRIDE=64).
// ---------------------------------------------------------------------------
__global__ __launch_bounds__(256) void wsoftmax_mfma(
    const u16* __restrict__ QP, const u16* __restrict__ Mkh,
    float* __restrict__ Wb)
{
    __shared__ float Sred[128 * 67];        // 34304 B; head doubles as At/Bt
    u16* At = (u16*)Sred;                   // [128][40] fp16 = 10240 B
    u16* Bt = At + 128 * 40;                // [64][40]  fp16 =  5120 B
    const int tid = threadIdx.x;
    const int row0 = blockIdx.x * 128;
    const int lane = tid & 63, wv = tid >> 6;
    const int wr = wv * 32;                 // wave: 32 rows x 64 cols
    const int q = lane >> 4, c0 = lane & 15;

    floatx4 acc[2][4];
#pragma unroll
    for (int m = 0; m < 2; ++m)
#pragma unroll
        for (int n = 0; n < 4; ++n) acc[m][n] = (floatx4)0.f;

    for (int kt = 0; kt < DQ; kt += 32) {
#pragma unroll
        for (int i = 0; i < 3; ++i) {
            int c = tid + i * 256;          // [0,768)
            if (c < 512) {
                int r = c >> 2, seg = c & 3;
                *(uint4*)&At[r * 40 + seg * 8] =
                    *(const uint4*)(QP + (size_t)(row0 + r) * DQ + kt + seg * 8);
            } else {
                int cb = c - 512;
                int r = cb >> 2, seg = cb & 3;
                *(uint4*)&Bt[r * 40 + seg * 8] =
                    *(const uint4*)(Mkh + (size_t)r * DQ + kt + seg * 8);
            }
        }
        __syncthreads();
        half8 af[2], bf[4];
#pragma unroll
        for (int m = 0; m < 2; ++m) af[m] = *(half8*)&At[(wr + m * 16 + c0) * 40 + q * 8];
#pragma unroll
        for (int n = 0; n < 4; ++n) bf[n] = *(half8*)&Bt[(n * 16 + c0) * 40 + q * 8];
#pragma unroll
        for (int m = 0; m < 2; ++m)
#pragma unroll
            for (int n = 0; n < 4; ++n)
                acc[m][n] = __builtin_amdgcn_mfma_f32_16x16x32_f16(af[m], bf[n], acc[m][n], 0, 0, 0);
        __syncthreads();
    }

    // dump logits to LDS: row = wr + m*16 + q*4 + r, col = n*16 + c0
#pragma unroll
    for (int m = 0; m < 2; ++m)
#pragma unroll
        for (int r4 = 0; r4 < 4; ++r4) {
            int row = wr + m * 16 + q * 4 + r4;
#pragma unroll
            for (int n = 0; n < 4; ++n)
                Sred[row * 67 + n * 16 + c0] = acc[m][n][r4];
        }
    __syncthreads();

    // row-wise softmax over 50 live cols; zero pad cols 50..63
    if (tid < 128) {
        float* s = &Sred[tid * 67];
        float mx = -3.0e38f;
#pragma unroll
        for (int m = 0; m < MM; ++m) mx = fmaxf(mx, s[m]);
        float sum = 0.f;
#pragma unroll
        for (int m = 0; m < MM; ++m) { float e = __expf(s[m] - mx); s[m] = e; sum += e; }
        float inv = 1.f / sum;
#pragma unroll
        for (int m = 0; m < MM; ++m) s[m] *= inv;
#pragma unroll
        for (int m = MM; m < 64; ++m) s[m] = 0.f;
    }
    __syncthreads();

    // coalesced store: 128 rows x 16 float4
    for (int i = tid; i < 128 * 16; i += 256) {
        int row = i >> 4, seg = i & 15;
        float4 v;
        v.x = Sred[row * 67 + seg * 4 + 0];
        v.y = Sred[row * 67 + seg * 4 + 1];
        v.z = Sred[row * 67 + seg * 4 + 2];
        v.w = Sred[row * 67 + seg * 4 + 3];
        *(float4*)(Wb + (size_t)(row0 + row) * WSTRIDE + seg * 4) = v;
    }
}

// ---------------------------------------------------------------------------
// DKVMN scan v3: 256 blocks (batch b) x 1024 threads (16 waves = 4/SIMD).
// m-dim split 4-way across lane groups (wave = 16 d x 4 mg); each thread
// owns mv[16] + w[16] in regs; w read per-thread from global (L1-resident,
// no LDS, no barriers); one-step software pipeline; reads combined via
// 2x shfl_xor.
// ---------------------------------------------------------------------------
__global__ __launch_bounds__(1024, 4) void scan_kernel(
    const float* __restrict__ Wb, const u32* __restrict__ EA,
    const float* __restrict__ Mv0, float* __restrict__ MvSt,
    u16* __restrict__ RDIE, int CS, int first)
{
    const int b = blockIdx.x;
    const int tid = threadIdx.x;
    const int lane = tid & 63;
    const int wave = tid >> 6;
    const int mg = lane >> 4;        // 0..3
    const int dl = lane & 15;
    const int d = wave * 16 + dl;    // 0..255
    const int m0 = mg * 16;

    float mv[16];
#pragma unroll
    for (int j = 0; j < 16; ++j) {
        int m = m0 + j;
        float v = 0.f;
        if (m < MM) v = first ? Mv0[m * DV + d] : MvSt[((size_t)b * MM + m) * DV + d];
        mv[j] = v;
    }

    const float* wrow = Wb + ((size_t)b * CS) * WSTRIDE + m0;
    const u32* ep = EA + ((size_t)b * CS) * DV + d;
    u16* rp = RDIE + ((size_t)b * CS) * 384 + d;

    float wc[16];
#pragma unroll
    for (int i = 0; i < 4; ++i) *(float4*)&wc[i * 4] = ld4(wrow + i * 4);
    u32 eac = *ep;

    for (int s = 0; s < CS; ++s) {
        // prefetch step s+1 (clamped at tail; offset 64 or 0 floats)
        const int adv = (s + 1 < CS) ? WSTRIDE : 0;
        float wn[16];
#pragma unroll
        for (int i = 0; i < 4; ++i) *(float4*)&wn[i * 4] = ld4(wrow + adv + i * 4);
        u32 ean = ep[(adv ? DV : 0)];

        const float e = h2f((u16)(eac & 0xffff));
        const float a = h2f((u16)(eac >> 16));

        float r = 0.f;
#pragma unroll
        for (int j = 0; j < 16; ++j) r = fmaf(wc[j], mv[j], r);
        r += __shfl_xor(r, 16);
        r += __shfl_xor(r, 32);
        if (mg == 0) rp[0] = f2h(r);

#pragma unroll
        for (int j = 0; j < 16; ++j) {
            float wm = wc[j];
            mv[j] = fmaf(mv[j], fmaf(-wm, e, 1.f), wm * a);
        }

#pragma unroll
        for (int j = 0; j < 16; ++j) wc[j] = wn[j];
        eac = ean;
        wrow += WSTRIDE; ep += DV; rp += 384;
    }

#pragma unroll
    for (int j = 0; j < 16; ++j) {
        int m = m0 + j;
        if (m < MM) MvSt[((size_t)b * MM + m) * DV + d] = mv[j];
    }
}

// ---------------------------------------------------------------------------
// loss + outputs
// ---------------------------------------------------------------------------
__global__ __launch_bounds__(256) void loss_part(
    const float* __restrict__ P, const int* __restrict__ target,
    const float* __restrict__ pred_b, float* __restrict__ out,
    float* __restrict__ R2, int s0, int CS, int Nc)
{
    int l = blockIdx.x * 256 + threadIdx.x;
    float le = 0.f, mf = 0.f;
    if (l < Nc) {
        int n = gmap(l, s0, CS);
        float p = P[l] + pred_b[0];
        int t = target[n];
        float y = (t >= 1) ? (float)(t - 1) : 0.f;
        float sig = 1.f / (1.f + __expf(-p));
        if (t >= 1) {
            mf = 1.f;
            le = fmaxf(p, 0.f) + log1pf(__expf(-fabsf(p))) - p * y;
        }
        out[1 + n] = sig * mf;
        out[1 + NROWS + n] = y * mf;
    }
#pragma unroll
    for (int off = 32; off; off >>= 1) {
        le += __shfl_down(le, off);
        mf += __shfl_down(mf, off);
    }
    __shared__ float sl[4], sm[4];
    int wid = threadIdx.x >> 6;
    if ((threadIdx.x & 63) == 0) { sl[wid] = le; sm[wid] = mf; }
    __syncthreads();
    if (threadIdx.x == 0) {
        atomicAdd(R2, sl[0] + sl[1] + sl[2] + sl[3]);
        atomicAdd(R2 + 1, sm[0] + sm[1] + sm[2] + sm[3]);
    }
}

__global__ void loss_fin(const float* __restrict__ R2, float* __restrict__ out)
{
    out[0] = R2[0] / fmaxf(R2[1], 1.f);
}

// ---------------------------------------------------------------------------
extern "C" void kernel_launch(void* const* d_in, const int* in_sizes, int n_in,
                              void* d_out, int out_size, void* d_ws, size_t ws_size,
                              hipStream_t stream)
{
    const int* q_data       = (const int*)d_in[0];
    const int* qa_data      = (const int*)d_in[1];
    const int* target       = (const int*)d_in[2];
    const int* time_data    = (const int*)d_in[3];
    const int* attempt_data = (const int*)d_in[4];
    const int* hint_data    = (const int*)d_in[5];
    const int* hintT_data   = (const int*)d_in[6];
    const float* q_emb    = (const float*)d_in[7];
    const float* qa_emb   = (const float*)d_in[8];
    const float* time_emb = (const float*)d_in[9];
    const float* att_emb  = (const float*)d_in[10];
    const float* ht_emb   = (const float*)d_in[11];
    const float* Mk       = (const float*)d_in[12];
    const float* Mv0      = (const float*)d_in[13];
    const float* diff_W   = (const float*)d_in[14];
    const float* diff_b   = (const float*)d_in[15];
    const float* diff2_W  = (const float*)d_in[16];
    const float* diff2_b  = (const float*)d_in[17];
    const float* erase_W  = (const float*)d_in[18];
    const float* erase_b  = (const float*)d_in[19];
    const float* add_W    = (const float*)d_in[20];
    const float* add_b    = (const float*)d_in[21];
    const float* read_W   = (const float*)d_in[22];
    const float* read_b   = (const float*)d_in[23];
    const float* pred_W   = (const float*)d_in[24];
    const float* pred_b   = (const float*)d_in[25];
    float* out = (float*)d_out;
    (void)in_sizes; (void)n_in; (void)out_size;

    // Adaptive chunking over S (any divisor of 500 works for scan v3).
    // Per-row bytes: wbuf 256 + bufP 4 + EAu 1024 + Xp 512 + S3p 256 +
    // QEp 256 + RDIE 768 = 3076 -> use 3080. FIXED ~24.1 MB.
    static const int cs_opts[] = {500, 250, 125, 100, 50, 25, 20, 10, 5, 4, 2};
    const size_t FIXED = 24100000ull;
    int CS = 0;
    for (int i = 0; i < 11; ++i) {
        size_t need = (size_t)NB * cs_opts[i] * 3080ull + FIXED;
        if (need <= ws_size) { CS = cs_opts[i]; break; }
    }
    if (CS == 0) return;
    const int NCH = SQ / CS;
    const int Nc = NB * CS;

    // Workspace layout (16B-aligned sections)
    float* MvSt  = (float*)d_ws;                         // [NB*MM*DV]
    float* wbuf  = MvSt + (size_t)NB * MM * DV;          // [Nc*64]
    float* bufP  = wbuf + (size_t)Nc * WSTRIDE;          // [Nc]
    float* bufR2 = bufP + Nc;                            // [4]
    u32*  EAu    = (u32*)(bufR2 + 4);                    // [Nc*256]
    u16*  Xp     = (u16*)(EAu + (size_t)Nc * 256);       // [2Nc*128]
    u16*  S3p    = Xp + (size_t)2 * Nc * 128;            // [Nc*128]
    u16*  QEp    = S3p + (size_t)Nc * 128;               // [Nc*128]
    u16*  RDIE   = QEp + (size_t)Nc * 128;               // [Nc*384]
    u16*  dWh    = RDIE + (size_t)Nc * 384;              // 16384
    u16*  d2Wh   = dWh + 16384;                          // 16384
    u16*  eWh    = d2Wh + 16384;                         // 65536
    u16*  aWh    = eWh + 65536;                          // 65536
    u16*  rWh    = aWh + 65536;                          // 196608
    u16*  qaEh   = rWh + 196608;                         // 5,120,256
    u16*  Mkh    = qaEh + 5120256;                       // 8,192 (64x128)

    // One-time weight/table conversions to fp16
    cvt16<<<16, 256, 0, stream>>>(diff_W,  dWh,  16384 / 4);
    cvt16<<<16, 256, 0, stream>>>(diff2_W, d2Wh, 16384 / 4);
    cvt16<<<64, 256, 0, stream>>>(erase_W, eWh,  65536 / 4);
    cvt16<<<64, 256, 0, stream>>>(add_W,   aWh,  65536 / 4);
    cvt16<<<192, 256, 0, stream>>>(read_W, rWh,  196608 / 4);
    cvt16<<<5001, 256, 0, stream>>>(qa_emb, qaEh, 5120256 / 4);
    mkcvt<<<8, 256, 0, stream>>>(Mk, Mkh);
    hipMemsetAsync(bufR2, 0, 4 * sizeof(float), stream);

    for (int c = 0; c < NCH; ++c) {
        const int s0 = c * CS;

        prep128<<<Nc / 8, 256, 0, stream>>>(
            q_data, time_data, attempt_data, hint_data, hintT_data,
            q_emb, time_emb, att_emb, ht_emb, Xp, S3p, QEp, s0, CS, Nc);

        // G1: [T1;T2] = tanh(lin1([X1;X2]))  (in-place Xp, 2Nc rows)
        gemm16<1><<<dim3(2 * Nc / 128, 1), 256, 0, stream>>>(
            Xp, dWh, nullptr, diff_b, nullptr, Xp, nullptr,
            nullptr, nullptr, nullptr, nullptr, nullptr, nullptr, 128, Nc, s0, CS);
        // G2: sig(lin2): rows<Nc -> tf; rows>=Nc -> x3 = qe + df*s3  (in-place)
        gemm16<2><<<dim3(2 * Nc / 128, 1), 256, 0, stream>>>(
            Xp, d2Wh, nullptr, diff2_b, nullptr, Xp, nullptr,
            QEp, S3p, nullptr, nullptr, nullptr, nullptr, 128, Nc, s0, CS);
        // G3: qp = lin1(x3) -> Xp[0:Nc); fused ie = qp + tf*te -> RDIE[:,256:)
        gemm16<3><<<dim3(Nc / 128, 1), 256, 0, stream>>>(
            Xp + (size_t)Nc * 128, dWh, nullptr, diff_b, nullptr, Xp, nullptr,
            nullptr, nullptr, time_data, time_emb, RDIE, nullptr, 128, Nc, s0, CS);
        // w = softmax(qp @ Mk^T) via MFMA
        wsoftmax_mfma<<<Nc / 128, 256, 0, stream>>>(Xp, Mkh, wbuf);
        // G4: e/a gates, gather-A from fp16 qa_emb, packed (e,a) -> EAu
        gemm16<4><<<dim3(Nc / 128, 4), 256, 0, stream>>>(
            qaEh, eWh, aWh, erase_b, add_b, nullptr, nullptr,
            nullptr, nullptr, qa_data, nullptr, (u16*)EAu, nullptr, 256, Nc, s0, CS);
        // scan v3 -> RD fp16 into RDIE[:,0:256)
        scan_kernel<<<NB, 1024, 0, stream>>>(wbuf, EAu, Mv0, MvSt, RDIE, CS, c == 0 ? 1 : 0);

        hipMemsetAsync(bufP, 0, (size_t)Nc * sizeof(float), stream);
        // G5: rc = tanh([rd|ie] @ read_W^T + b); pred partials -> bufP
        gemm16<5><<<dim3(Nc / 128, 4), 256, 0, stream>>>(
            RDIE, rWh, nullptr, read_b, nullptr, nullptr, bufP,
            nullptr, nullptr, nullptr, nullptr, nullptr, pred_W, 384, Nc, s0, CS);

        loss_part<<<Nc / 256, 256, 0, stream>>>(bufP, target, pred_b, out, bufR2, s0, CS, Nc);
    }

    loss_fin<<<1, 1, 0, stream>>>(bufR2, out);
}